// Round 4
// baseline (388.919 us; speedup 1.0000x reference)
//
#include <hip/hip_runtime.h>
#include <hip/hip_bf16.h>

#define B_ 4
#define S_ 2048
#define D_ 1024
#define H_ 16
#define HD_ 64
#define M_ (B_*S_)

typedef __bf16 bf16;
typedef bf16 bf16x8 __attribute__((ext_vector_type(8)));
typedef bf16 bf16x4 __attribute__((ext_vector_type(4)));
typedef float f32x4 __attribute__((ext_vector_type(4)));

__device__ __forceinline__ void gload_lds16(const void* g, void* l) {
  __builtin_amdgcn_global_load_lds((const __attribute__((address_space(1))) void*)g,
                                   (__attribute__((address_space(3))) void*)l, 16, 0, 0);
}

// ---------------------------------------------------------------- weights T
// vectorized: float4 reads, bf16x8 writes
__global__ __launch_bounds__(256)
void wtrans_kernel(const float* __restrict__ Wq, const float* __restrict__ Wk,
                   const float* __restrict__ Wv, const float* __restrict__ Wo,
                   bf16* __restrict__ Wqt, bf16* __restrict__ Wkt,
                   bf16* __restrict__ Wvt, bf16* __restrict__ Wot) {
  __shared__ float tile[64][68];  // 68: rows stay 16B-aligned, banks spread
  const float* W; bf16* Wt;
  switch (blockIdx.z) {
    case 0: W = Wq; Wt = Wqt; break;
    case 1: W = Wk; Wt = Wkt; break;
    case 2: W = Wv; Wt = Wvt; break;
    default: W = Wo; Wt = Wot; break;
  }
  const int n0 = blockIdx.x * 64, k0 = blockIdx.y * 64;
  const int tid = threadIdx.x;
#pragma unroll
  for (int i = 0; i < 4; i++) {
    int f = tid + i * 256;
    int k = f >> 4, c = f & 15;
    float4 v = *(const float4*)(W + (size_t)(k0 + k) * D_ + n0 + c * 4);
    *(float4*)(&tile[k][c * 4]) = v;
  }
  __syncthreads();
#pragma unroll
  for (int i = 0; i < 2; i++) {
    int f = tid + i * 256;
    int n = f >> 3, c = f & 7;
    bf16x8 o;
#pragma unroll
    for (int j = 0; j < 8; j++) o[j] = (bf16)tile[c * 8 + j][n];
    *(bf16x8*)(Wt + (size_t)(n0 + n) * D_ + k0 + c * 8) = o;
  }
}

// ---------------------------------------------------------------- QKV proj
// A: register-prefetch fp32 -> packed cvt -> bf16 LDS (ds_write_b128).
// B: glds bf16, XOR-8 swizzle. LDS 32 KB. BK=64.
#define QSCALE 0.18033688011112042f  // 1/sqrt(HD) * log2(e)

__global__ __launch_bounds__(256)
void proj_gemm_kernel(const float* __restrict__ Aq, const float* __restrict__ Ak,
                      const float* __restrict__ Av,
                      const bf16* __restrict__ Wqt, const bf16* __restrict__ Wkt,
                      const bf16* __restrict__ Wvt,
                      const float* __restrict__ bq, const float* __restrict__ bk,
                      const float* __restrict__ bv,
                      bf16* __restrict__ qb, bf16* __restrict__ kb, bf16* __restrict__ vbT) {
  __shared__ bf16 As[128 * 64];  // 16 KB
  __shared__ bf16 Bs[128 * 64];  // 16 KB
  const float* A; const bf16* Bt; const float* bias;
  if (blockIdx.z == 0)      { A = Aq; Bt = Wqt; bias = bq; }
  else if (blockIdx.z == 1) { A = Ak; Bt = Wkt; bias = bk; }
  else                      { A = Av; Bt = Wvt; bias = bv; }

  const int n0 = blockIdx.x * 128, m0 = blockIdx.y * 128;
  const int tid = threadIdx.x;
  const int lane = tid & 63, w = tid >> 6;
  const int wr = w >> 1, wc = w & 1;
  const int l15 = lane & 15, quad = lane >> 4;
  const int srow = lane >> 3, schunk = lane & 7;

  f32x4 acc[4][4] = {};
  float4 Ar[4][2];  // prefetched A fp32: 4 row-groups x 2 float4 (8 cols)

  auto loadA = [&](int kt) {
    const int k0 = kt * 64;
#pragma unroll
    for (int t = 0; t < 4; t++) {
      const float* p = A + (size_t)(m0 + w * 32 + t * 8 + srow) * D_ + k0 + schunk * 8;
      Ar[t][0] = *(const float4*)p;
      Ar[t][1] = *(const float4*)(p + 4);
    }
  };

  loadA(0);

  for (int kt = 0; kt < D_ / 64; kt++) {
    const int k0 = kt * 64;
    // stage B via glds (XOR-8 on global chunk)
#pragma unroll
    for (int t = 0; t < 4; t++) {
      int r0 = w * 32 + t * 8;
      int row = r0 + srow;
      int cg = schunk ^ (row & 7);
      gload_lds16(Bt + (size_t)(n0 + row) * D_ + k0 + cg * 8, &Bs[r0 * 64]);
    }
    // stage A from regs: cvt + ds_write_b128 (XOR-8 on LDS chunk)
#pragma unroll
    for (int t = 0; t < 4; t++) {
      int row = w * 32 + t * 8 + srow;
      int c = schunk ^ (row & 7);
      bf16x8 v;
      v[0] = (bf16)Ar[t][0].x; v[1] = (bf16)Ar[t][0].y;
      v[2] = (bf16)Ar[t][0].z; v[3] = (bf16)Ar[t][0].w;
      v[4] = (bf16)Ar[t][1].x; v[5] = (bf16)Ar[t][1].y;
      v[6] = (bf16)Ar[t][1].z; v[7] = (bf16)Ar[t][1].w;
      *(bf16x8*)(&As[row * 64 + c * 8]) = v;
    }
    __syncthreads();

    if (kt + 1 < D_ / 64) loadA(kt + 1);  // latency hidden under compute

#pragma unroll
    for (int ks = 0; ks < 2; ks++) {
      bf16x8 a[4], b[4];
#pragma unroll
      for (int fm = 0; fm < 4; fm++) {
        int row = wr * 64 + fm * 16 + l15;
        a[fm] = *(const bf16x8*)(&As[row * 64 + (((ks * 4 + quad) ^ (row & 7)) * 8)]);
      }
#pragma unroll
      for (int fn = 0; fn < 4; fn++) {
        int row = wc * 64 + fn * 16 + l15;
        b[fn] = *(const bf16x8*)(&Bs[row * 64 + (((ks * 4 + quad) ^ (row & 7)) * 8)]);
      }
#pragma unroll
      for (int fm = 0; fm < 4; fm++)
#pragma unroll
        for (int fn = 0; fn < 4; fn++)
          acc[fm][fn] = __builtin_amdgcn_mfma_f32_16x16x32_bf16(a[fm], b[fn], acc[fm][fn], 0, 0, 0);
    }
    __syncthreads();
  }

  // epilogue: +bias, *scale -> bf16.  Q/K: [M][D].  V: transposed [D][M].
  if (blockIdx.z < 2) {
    bf16* C = (blockIdx.z == 0) ? qb : kb;
    float scale = (blockIdx.z == 0) ? QSCALE : 1.0f;
#pragma unroll
    for (int fm = 0; fm < 4; fm++) {
      int row = m0 + wr * 64 + fm * 16 + quad * 4;
#pragma unroll
      for (int fn = 0; fn < 4; fn++) {
        int col = n0 + wc * 64 + fn * 16 + l15;
        float bval = bias[col];
#pragma unroll
        for (int r = 0; r < 4; r++)
          C[(size_t)(row + r) * D_ + col] = (bf16)((acc[fm][fn][r] + bval) * scale);
      }
    }
  } else {
#pragma unroll
    for (int fm = 0; fm < 4; fm++) {
      int row = m0 + wr * 64 + fm * 16 + quad * 4;
#pragma unroll
      for (int fn = 0; fn < 4; fn++) {
        int col = n0 + wc * 64 + fn * 16 + l15;
        float bval = bias[col];
        bf16x4 pk;
#pragma unroll
        for (int r = 0; r < 4; r++) pk[r] = (bf16)(acc[fm][fn][r] + bval);
        *(bf16x4*)(vbT + (size_t)col * M_ + row) = pk;
      }
    }
  }
}

// ---------------------------------------------------------------- attention
// Block covers 256 q (4 waves x 64q). K/V tiles [64][64] double-buffered,
// Ps [256][64] XOR-swizzled. LDS = 16+16+32 = 64 KB exactly.
__global__ __launch_bounds__(256)
void attn_kernel(const bf16* __restrict__ qb, const bf16* __restrict__ kb,
                 const bf16* __restrict__ vbT, bf16* __restrict__ ctxb) {
  __shared__ bf16 Ks[2][64 * 64];
  __shared__ bf16 Vs[2][64 * 64];
  __shared__ bf16 Ps[256 * 64];

  const int bh = blockIdx.y;
  const int b = bh >> 4, h = bh & 15;
  const int q0 = blockIdx.x * 256;
  const int tid = threadIdx.x, lane = tid & 63, w = tid >> 6;
  const int l15 = lane & 15, quad = lane >> 4;

  const size_t baseQ = ((size_t)(b * S_ + q0)) * D_ + h * HD_;

  // Q fragments (pre-scaled by log2e/8): wave w -> q rows [w*64, w*64+64)
  bf16x8 qf[4][2];
#pragma unroll
  for (int fq = 0; fq < 4; fq++)
#pragma unroll
    for (int ks = 0; ks < 2; ks++)
      qf[fq][ks] = *(const bf16x8*)(qb + baseQ + (size_t)(w * 64 + fq * 16 + l15) * D_ + ks * 32 + quad * 8);

  f32x4 o[4][4] = {};
  float li[4] = {};  // lane-local row-sum for q = fq*16 + l15

  const int srow_i = lane >> 3;
  const int schunk = lane & 7;

  auto stage = [&](int buf, int kt) {
#pragma unroll
    for (int t = 0; t < 2; t++) {
      const int r0 = w * 16 + t * 8;
      const int row = r0 + srow_i;
      const int c = schunk ^ (row & 7);
      const bf16* gK = kb + ((size_t)(b * S_ + kt * 64 + row)) * D_ + h * 64 + c * 8;
      gload_lds16(gK, &Ks[buf][r0 * 64]);
      const bf16* gV = vbT + ((size_t)(h * 64 + row)) * M_ + b * S_ + kt * 64 + c * 8;
      gload_lds16(gV, &Vs[buf][r0 * 64]);
    }
  };

  stage(0, 0);
  __syncthreads();

  for (int kt = 0; kt < S_ / 64; kt++) {
    const int buf = kt & 1;
    if (kt + 1 < S_ / 64) stage(buf ^ 1, kt + 1);

    // S^T[64 keys][64 q] per wave: st[fk][fq], lane: q=l15, key=quad*4+r
    f32x4 st[4][4] = {};
#pragma unroll
    for (int ks = 0; ks < 2; ks++) {
#pragma unroll
      for (int fk = 0; fk < 4; fk++) {
        const int key = fk * 16 + l15;
        bf16x8 kf = *(const bf16x8*)(&Ks[buf][key * 64 + (((ks * 4 + quad) ^ (key & 7)) * 8)]);
#pragma unroll
        for (int fq = 0; fq < 4; fq++)
          st[fk][fq] = __builtin_amdgcn_mfma_f32_16x16x32_bf16(kf, qf[fq][ks], st[fk][fq], 0, 0, 0);
      }
    }

    // flat softmax: p = exp2(s); pack 4 consecutive keys -> 8B store.
    // Ps swizzle: elem = row*64 + ((chunk) ^ (row&7))*8 + (quad&1)*4,
    // chunk = fk*2 + (quad>>1), row = w*64 + fq*16 + l15.
#pragma unroll
    for (int fq = 0; fq < 4; fq++) {
      const int row = w * 64 + fq * 16 + l15;
#pragma unroll
      for (int fk = 0; fk < 4; fk++) {
        float p0 = __builtin_amdgcn_exp2f(st[fk][fq][0]);
        float p1 = __builtin_amdgcn_exp2f(st[fk][fq][1]);
        float p2 = __builtin_amdgcn_exp2f(st[fk][fq][2]);
        float p3 = __builtin_amdgcn_exp2f(st[fk][fq][3]);
        li[fq] += (p0 + p1) + (p2 + p3);
        bf16x4 pk;
        pk[0] = (bf16)p0; pk[1] = (bf16)p1; pk[2] = (bf16)p2; pk[3] = (bf16)p3;
        const int chunk = (fk * 2 + (quad >> 1)) ^ (row & 7);
        *(bf16x4*)(&Ps[row * 64 + chunk * 8 + (quad & 1) * 4]) = pk;
      }
    }

    // PV: O[64q][64d] += P * V   (wave-private P rows, no barrier)
#pragma unroll
    for (int ks2 = 0; ks2 < 2; ks2++) {
      bf16x8 pf[4], vf[4];
#pragma unroll
      for (int fm = 0; fm < 4; fm++) {
        const int row = w * 64 + fm * 16 + l15;
        pf[fm] = *(const bf16x8*)(&Ps[row * 64 + (((ks2 * 4 + quad) ^ (row & 7)) * 8)]);
      }
#pragma unroll
      for (int fd = 0; fd < 4; fd++) {
        const int d = fd * 16 + l15;
        vf[fd] = *(const bf16x8*)(&Vs[buf][d * 64 + (((ks2 * 4 + quad) ^ (d & 7)) * 8)]);
      }
#pragma unroll
      for (int fm = 0; fm < 4; fm++)
#pragma unroll
        for (int fd = 0; fd < 4; fd++)
          o[fm][fd] = __builtin_amdgcn_mfma_f32_16x16x32_bf16(pf[fm], vf[fd], o[fm][fd], 0, 0, 0);
    }
    __syncthreads();  // staging of next buf done; all waves done with buf
  }

  // epilogue: reduce li across quads (q=l15), transpose via shfl, store
  float linv[4];
#pragma unroll
  for (int fq = 0; fq < 4; fq++) {
    float l = li[fq];
    l += __shfl_xor(l, 16);
    l += __shfl_xor(l, 32);
    linv[fq] = 1.0f / l;  // valid for q = fq*16 + l15, uniform over quads
  }
#pragma unroll
  for (int fq = 0; fq < 4; fq++) {
#pragma unroll
    for (int r = 0; r < 4; r++) {
      float inv = __shfl(linv[fq], quad * 4 + r);  // q-row = fq*16+quad*4+r
      int row = w * 64 + fq * 16 + quad * 4 + r;
#pragma unroll
      for (int fd = 0; fd < 4; fd++)
        ctxb[baseQ + (size_t)row * D_ + fd * 16 + l15] = (bf16)(o[fq][fd][r] * inv);
    }
  }
}

// ---------------------------------------------------------------- out proj
// m97-style bf16 GEMM: BK=64, glds staging, XOR-8 swizzle (unchanged).
__global__ __launch_bounds__(256)
void out_gemm_kernel(const bf16* __restrict__ A, const bf16* __restrict__ Bt,
                     const float* __restrict__ bias, float* __restrict__ Cout) {
  __shared__ bf16 As[128 * 64];
  __shared__ bf16 Bs[128 * 64];
  const int n0 = blockIdx.x * 128, m0 = blockIdx.y * 128;
  const int tid = threadIdx.x;
  const int lane = tid & 63, w = tid >> 6;
  const int wr = w >> 1, wc = w & 1;
  const int l15 = lane & 15, quad = lane >> 4;
  const int srow = lane >> 3, schunk = lane & 7;

  f32x4 acc[4][4] = {};

  for (int kt = 0; kt < D_ / 64; kt++) {
    const int k0 = kt * 64;
#pragma unroll
    for (int t = 0; t < 4; t++) {
      int r0 = w * 32 + t * 8;
      int row = r0 + srow;
      int cg = schunk ^ (row & 7);
      gload_lds16(A + (size_t)(m0 + row) * D_ + k0 + cg * 8, &As[r0 * 64]);
      gload_lds16(Bt + (size_t)(n0 + row) * D_ + k0 + cg * 8, &Bs[r0 * 64]);
    }
    __syncthreads();

#pragma unroll
    for (int ks = 0; ks < 2; ks++) {
      bf16x8 a[4], b[4];
#pragma unroll
      for (int fm = 0; fm < 4; fm++) {
        int row = wr * 64 + fm * 16 + l15;
        a[fm] = *(const bf16x8*)(&As[row * 64 + (((ks * 4 + quad) ^ (row & 7)) * 8)]);
      }
#pragma unroll
      for (int fn = 0; fn < 4; fn++) {
        int row = wc * 64 + fn * 16 + l15;
        b[fn] = *(const bf16x8*)(&Bs[row * 64 + (((ks * 4 + quad) ^ (row & 7)) * 8)]);
      }
#pragma unroll
      for (int fm = 0; fm < 4; fm++)
#pragma unroll
        for (int fn = 0; fn < 4; fn++)
          acc[fm][fn] = __builtin_amdgcn_mfma_f32_16x16x32_bf16(a[fm], b[fn], acc[fm][fn], 0, 0, 0);
    }
    __syncthreads();
  }
#pragma unroll
  for (int fm = 0; fm < 4; fm++) {
    int row = m0 + wr * 64 + fm * 16 + quad * 4;
#pragma unroll
    for (int fn = 0; fn < 4; fn++) {
      int col = n0 + wc * 64 + fn * 16 + l15;
      float bval = bias[col];
#pragma unroll
      for (int r = 0; r < 4; r++)
        Cout[(size_t)(row + r) * D_ + col] = acc[fm][fn][r] + bval;
    }
  }
}

// ---------------------------------------------------------------- launch
extern "C" void kernel_launch(void* const* d_in, const int* in_sizes, int n_in,
                              void* d_out, int out_size, void* d_ws, size_t ws_size,
                              hipStream_t stream) {
  const float* query = (const float*)d_in[0];
  const float* key   = (const float*)d_in[1];
  const float* value = (const float*)d_in[2];
  const float* Wq = (const float*)d_in[3];
  const float* bq = (const float*)d_in[4];
  const float* Wk = (const float*)d_in[5];
  const float* bk = (const float*)d_in[6];
  const float* Wv = (const float*)d_in[7];
  const float* bv = (const float*)d_in[8];
  const float* Wo = (const float*)d_in[9];
  const float* bo = (const float*)d_in[10];
  float* out = (float*)d_out;

  char* ws = (char*)d_ws;
  const size_t WT_BYTES = (size_t)D_ * D_ * sizeof(bf16);   // 2 MB
  const size_t MD_BYTES = (size_t)M_ * D_ * sizeof(bf16);   // 16 MB
  bf16* Wqt  = (bf16*)(ws);
  bf16* Wkt  = (bf16*)(ws + WT_BYTES);
  bf16* Wvt  = (bf16*)(ws + 2 * WT_BYTES);
  bf16* Wot  = (bf16*)(ws + 3 * WT_BYTES);
  bf16* qb   = (bf16*)(ws + 4 * WT_BYTES);
  bf16* kb   = (bf16*)(ws + 4 * WT_BYTES + MD_BYTES);
  bf16* vbT  = (bf16*)(ws + 4 * WT_BYTES + 2 * MD_BYTES);
  bf16* ctxb = (bf16*)(ws + 4 * WT_BYTES + 3 * MD_BYTES);

  wtrans_kernel<<<dim3(D_ / 64, D_ / 64, 4), 256, 0, stream>>>(
      Wq, Wk, Wv, Wo, Wqt, Wkt, Wvt, Wot);

  proj_gemm_kernel<<<dim3(D_ / 128, M_ / 128, 3), 256, 0, stream>>>(
      query, key, value, Wqt, Wkt, Wvt, bq, bk, bv, qb, kb, vbT);

  attn_kernel<<<dim3(S_ / 256, B_ * H_), 256, 0, stream>>>(qb, kb, vbT, ctxb);

  out_gemm_kernel<<<dim3(D_ / 128, M_ / 128), 256, 0, stream>>>(ctxb, Wot, bo, out);
}